// Round 1
// baseline (397.761 us; speedup 1.0000x reference)
//
#include <hip/hip_runtime.h>
#include <cstdint>
#include <cstddef>

#define BSZ 16
#define LQ  512
#define HIDDIM 768
#define NH  12
#define HD  64
#define R2V 16
#define NTOT 1536   // K columns (768) + V columns (768)

// ---------------------------------------------------------------------------
// Kernel 1: dual GEMM  C[m,n] = relu(sum_k A[m,k]*W[n,k] + bias[n])
//   n in [0,768)    -> K1buf
//   n in [768,1536) -> V1buf
// 64x64 tile, BK=16, 256 threads, 4x4 microtile per thread.
// ---------------------------------------------------------------------------
#define BM 64
#define BN 64
#define BK 16

__global__ __launch_bounds__(256) void gemm_kv(
    const float* __restrict__ A,
    const float* __restrict__ Kw, const float* __restrict__ Kb,
    const float* __restrict__ Vw, const float* __restrict__ Vb,
    float* __restrict__ K1, float* __restrict__ V1)
{
    // +4 pad keeps 16B alignment for b128 reads and <=2-way bank aliasing
    __shared__ float As[BK][BM + 4];
    __shared__ float Bs[BK][BN + 4];

    const int n0  = blockIdx.x * BN;
    const int m0  = blockIdx.y * BM;
    const int tid = threadIdx.x;
    const int tx  = tid & 15;   // 0..15 -> n
    const int ty  = tid >> 4;   // 0..15 -> m

    const bool isK = (n0 < HIDDIM);
    const float* __restrict__ W    = isK ? Kw : Vw;
    const float* __restrict__ bias = isK ? Kb : Vb;
    float* __restrict__ dst        = isK ? K1 : V1;
    const int ncol0 = isK ? n0 : (n0 - HIDDIM);

    float acc[4][4];
    #pragma unroll
    for (int i = 0; i < 4; ++i)
        #pragma unroll
        for (int j = 0; j < 4; ++j) acc[i][j] = 0.f;

    const int lr = tid >> 2;        // 0..63 : tile row
    const int lc = (tid & 3) * 4;   // 0,4,8,12 : tile col (k)

    for (int k0 = 0; k0 < HIDDIM; k0 += BK) {
        float4 av = *(const float4*)(A + (size_t)(m0 + lr) * HIDDIM + k0 + lc);
        float4 bv = *(const float4*)(W + (size_t)(ncol0 + lr) * HIDDIM + k0 + lc);
        As[lc + 0][lr] = av.x; As[lc + 1][lr] = av.y;
        As[lc + 2][lr] = av.z; As[lc + 3][lr] = av.w;
        Bs[lc + 0][lr] = bv.x; Bs[lc + 1][lr] = bv.y;
        Bs[lc + 2][lr] = bv.z; Bs[lc + 3][lr] = bv.w;
        __syncthreads();

        #pragma unroll
        for (int kk = 0; kk < BK; ++kk) {
            float a[4], b[4];
            #pragma unroll
            for (int i = 0; i < 4; ++i) a[i] = As[kk][ty * 4 + i];
            #pragma unroll
            for (int j = 0; j < 4; ++j) b[j] = Bs[kk][tx * 4 + j];
            #pragma unroll
            for (int i = 0; i < 4; ++i)
                #pragma unroll
                for (int j = 0; j < 4; ++j)
                    acc[i][j] += a[i] * b[j];
        }
        __syncthreads();
    }

    // epilogue: bias + relu, vectorized float4 store
    #pragma unroll
    for (int i = 0; i < 4; ++i) {
        const int m  = m0 + ty * 4 + i;
        const int nc = ncol0 + tx * 4;
        float4 v;
        v.x = fmaxf(acc[i][0] + bias[nc + 0], 0.f);
        v.y = fmaxf(acc[i][1] + bias[nc + 1], 0.f);
        v.z = fmaxf(acc[i][2] + bias[nc + 2], 0.f);
        v.w = fmaxf(acc[i][3] + bias[nc + 3], 0.f);
        *(float4*)(dst + (size_t)m * HIDDIM + nc) = v;
    }
}

// ---------------------------------------------------------------------------
// Kernel 2: per (b,h): scores -> softmax(+exp(-m) residual) -> events ->
// col0/col1 scans -> event-time list + prefix count -> materialize idx[l][16].
// One block of 512 threads per (b,h); thread == position l.
// ---------------------------------------------------------------------------
__global__ __launch_bounds__(512) void scores_scan(
    const float* __restrict__ K1,
    const float* __restrict__ rh,
    int* __restrict__ idxbuf)
{
    const int bh = blockIdx.x;          // 0..191
    const int b  = bh / NH;
    const int h  = bh % NH;
    const int l  = threadIdx.x;         // 0..511

    __shared__ float red[LQ];
    __shared__ int   ev[LQ];
    __shared__ int   scn[LQ];
    __shared__ int   col0[LQ];
    __shared__ int   col1[LQ];
    __shared__ int   csum[LQ];
    __shared__ int   E[LQ];

    // ---- 1. score[l] = dot64(relu'd K1 row, reading_head[h]) ----
    const float* krow = K1 + ((size_t)(b * LQ + l)) * HIDDIM + h * HD;
    const float* rrow = rh + h * HD;
    float s = 0.f;
    #pragma unroll
    for (int d = 0; d < HD; d += 4) {
        float4 kv = *(const float4*)(krow + d);
        float4 rv = *(const float4*)(rrow + d);
        s += kv.x * rv.x + kv.y * rv.y + kv.z * rv.z + kv.w * rv.w;
    }

    // ---- 2. softmax over L + residual, threshold ----
    red[l] = s; __syncthreads();
    for (int off = 256; off > 0; off >>= 1) {
        if (l < off) red[l] = fmaxf(red[l], red[l + off]);
        __syncthreads();
    }
    const float m = red[0];
    __syncthreads();
    const float e = expf(s - m);
    red[l] = e; __syncthreads();
    for (int off = 256; off > 0; off >>= 1) {
        if (l < off) red[l] += red[l + off];
        __syncthreads();
    }
    const float ssum = red[0];
    const float p = e / ssum + expf(-m);
    const int event = (p > (1.5f / 512.0f)) ? 1 : 0;
    ev[l] = event;
    __syncthreads();

    // ---- 3. col0: inclusive max-scan of (event ? l : -1) ----
    scn[l] = event ? l : -1; __syncthreads();
    for (int off = 1; off < LQ; off <<= 1) {
        int v = scn[l];
        if (l >= off) { int u = scn[l - off]; v = (u > v) ? u : v; }
        __syncthreads();
        scn[l] = v; __syncthreads();
    }
    col0[l] = (scn[l] >= 0) ? scn[l] : l;
    __syncthreads();

    // ---- 4. col1: suffix min-scan of (rolled[j]? j : BIG), rolled[j]=ev[(j+1)&511]
    scn[l] = ev[(l + 1) & (LQ - 1)] ? l : (1 << 30); __syncthreads();
    for (int off = 1; off < LQ; off <<= 1) {
        int v = scn[l];
        if (l + off < LQ) { int u = scn[l + off]; v = (u < v) ? u : v; }
        __syncthreads();
        scn[l] = v; __syncthreads();
    }
    col1[l] = (l == 0) ? 0 : (((scn[l] < (1 << 30)) ? scn[l] : l) + 1);
    __syncthreads();

    // ---- 5. prefix count of events over steps 1..l (inclusive) ----
    csum[l] = (l >= 1) ? event : 0; __syncthreads();
    for (int off = 1; off < LQ; off <<= 1) {
        int v = csum[l];
        if (l >= off) v += csum[l - off];
        __syncthreads();
        csum[l] = v; __syncthreads();
    }

    // ---- 6. event-time list ----
    if (l >= 1 && event) E[csum[l] - 1] = l;
    __syncthreads();

    // ---- 7. registers at l = pairs from last 8 event times <= l ----
    const int c = csum[l];
    int* op = idxbuf + ((size_t)(b * LQ + l) * NH + h) * R2V;
    #pragma unroll
    for (int j = 0; j < 8; ++j) {
        const int k = c - 1 - j;
        int f = 0, bb = 0;
        if (k >= 0) {
            const int t = E[k];       // t >= 1
            f  = col0[t - 1];
            bb = col1[t - 1];
        }
        f  = min(max(f, 0), LQ - 1);
        bb = min(max(bb, 0), LQ - 1);
        op[2 * j]     = f;
        op[2 * j + 1] = bb;
    }
}

// ---------------------------------------------------------------------------
// Kernel 3: out[b,l,h,:] = sum_r w[h,r] * V1[b, idx[b,l,h,r], h, :]
// 256 threads/block = 4 waves; each wave handles one (b,l,h), lane = d.
// ---------------------------------------------------------------------------
__global__ __launch_bounds__(256) void gather_out(
    const float* __restrict__ V1,
    const int* __restrict__ idxbuf,
    const float* __restrict__ w,
    float* __restrict__ out)
{
    const int g = blockIdx.x * 4 + (threadIdx.x >> 6);  // 0..98303 = (b*512+l)*12+h
    const int d = threadIdx.x & 63;
    const int h = g % NH;
    const int bl = g / NH;          // b*512 + l
    const int b  = bl / LQ;

    const int* ip = idxbuf + (size_t)g * R2V;
    const float* wp = w + h * R2V;

    float acc = 0.f;
    #pragma unroll
    for (int r = 0; r < R2V; ++r) {
        const int idx = ip[r];
        acc += wp[r] * V1[((size_t)(b * LQ + idx) * HIDDIM) + h * HD + d];
    }
    out[(size_t)g * HD + d] = acc;
}

// ---------------------------------------------------------------------------
extern "C" void kernel_launch(void* const* d_in, const int* in_sizes, int n_in,
                              void* d_out, int out_size, void* d_ws, size_t ws_size,
                              hipStream_t stream)
{
    (void)in_sizes; (void)n_in; (void)out_size; (void)ws_size;

    const float* hs = (const float*)d_in[0];   // (16,512,768)
    const float* Kw = (const float*)d_in[1];   // (768,768)
    const float* Kb = (const float*)d_in[2];   // (768,)
    const float* Vw = (const float*)d_in[3];   // (768,768)
    const float* Vb = (const float*)d_in[4];   // (768,)
    const float* rh = (const float*)d_in[5];   // (12,64)
    const float* bw = (const float*)d_in[6];   // (1,1,12,1,16) -> [h*16+r]
    float* out = (float*)d_out;                // (16,512,12,64) fp32

    // workspace layout: K1 (25.2MB) | V1 (25.2MB) | idx (6.3MB)  ~ 56.7MB
    float* K1 = (float*)d_ws;
    float* V1 = K1 + (size_t)BSZ * LQ * HIDDIM;
    int* idxbuf = (int*)(V1 + (size_t)BSZ * LQ * HIDDIM);

    dim3 g1(NTOT / BN, (BSZ * LQ) / BM);       // 24 x 128
    gemm_kv<<<g1, 256, 0, stream>>>(hs, Kw, Kb, Vw, Vb, K1, V1);

    scores_scan<<<BSZ * NH, LQ, 0, stream>>>(K1, rh, idxbuf);

    gather_out<<<(BSZ * LQ * NH) / 4, 256, 0, stream>>>(V1, idxbuf, bw, out);
}

// Round 2
// 169.048 us; speedup vs baseline: 2.3529x; 2.3529x over previous
//
#include <hip/hip_runtime.h>
#include <cstdint>
#include <cstddef>

#define BSZ 16
#define LQ  512
#define HIDDIM 768
#define NH  12
#define HD  64
#define R2V 16
#define NTOT 1536   // fused N: K cols [0,768) | V cols [768,1536)
#define MTOT 8192   // BSZ*LQ

typedef __bf16 bf16x8 __attribute__((ext_vector_type(8)));
typedef float  f32x4  __attribute__((ext_vector_type(4)));

__device__ inline unsigned short f2bf(float x) {
    union { float f; unsigned u; } c; c.f = x;
    unsigned r = c.u + 0x7fffu + ((c.u >> 16) & 1u);   // RNE (no NaN in inputs)
    return (unsigned short)(r >> 16);
}

// ---------------------------------------------------------------------------
// Kernel 0: cast hs + pack weights (K rows then V rows) to bf16; pack bias.
// One thread per float4. Exact grid: (NHS4+NW4)/256 blocks.
// ---------------------------------------------------------------------------
#define NHS4 1572864   // 16*512*768/4
#define NW1  147456    // 768*768/4
#define NW4  294912    // 2*768*768/4

__global__ __launch_bounds__(256) void cast_pack(
    const float* __restrict__ hs,
    const float* __restrict__ Kw, const float* __restrict__ Vw,
    const float* __restrict__ Kb, const float* __restrict__ Vb,
    unsigned short* __restrict__ hsb, unsigned short* __restrict__ Wb,
    float* __restrict__ biasp)
{
    const int i = blockIdx.x * 256 + threadIdx.x;
    float4 v; unsigned short* dst;
    if (i < NHS4) {
        v = ((const float4*)hs)[i];
        dst = hsb + (size_t)i * 4;
    } else {
        const int j = i - NHS4;
        v = (j < NW1) ? ((const float4*)Kw)[j] : ((const float4*)Vw)[j - NW1];
        dst = Wb + (size_t)j * 4;
    }
    ushort4 o;
    o.x = f2bf(v.x); o.y = f2bf(v.y); o.z = f2bf(v.z); o.w = f2bf(v.w);
    *(ushort4*)dst = o;
    if (i < 768) { biasp[i] = Kb[i]; biasp[768 + i] = Vb[i]; }
}

// ---------------------------------------------------------------------------
// Kernel 1: bf16 MFMA GEMM  C[m,n] = relu(sum_k A[m,k]*W[n,k] + bias[n])
// 128x128 tile, BK=32, 256 threads = 4 waves (2x2 of 64x64 wave tiles),
// 16x16x32 bf16 MFMA, global_load_lds width=16, fp32 epilogue.
// ---------------------------------------------------------------------------
#define TBM 128
#define TBN 128
#define TBK 32

#define GLD16(g, l) __builtin_amdgcn_global_load_lds( \
    (const __attribute__((address_space(1))) void*)(g), \
    (__attribute__((address_space(3))) void*)(l), 16, 0, 0)

__global__ __launch_bounds__(256) void gemm_mfma(
    const unsigned short* __restrict__ Abf,   // 8192 x 768 bf16 row-major
    const unsigned short* __restrict__ Wbf,   // 1536 x 768 bf16 row-major
    const float* __restrict__ biasp,          // 1536 fp32
    float* __restrict__ K1, float* __restrict__ V1)
{
    __shared__ unsigned short As[TBM * TBK];  // [m][k] k-contig, 8 KB
    __shared__ unsigned short Bs[TBN * TBK];  // [n][k] k-contig, 8 KB

    const int n0   = blockIdx.x * TBN;
    const int m0   = blockIdx.y * TBM;
    const int tid  = threadIdx.x;
    const int wid  = tid >> 6;
    const int lane = tid & 63;
    const int wm   = (wid & 1) * 64;
    const int wn   = (wid >> 1) * 64;

    f32x4 acc[4][4] = {};   // [mi][ni], 64 fp32/lane

    // staging: wave wid loads rows [wid*32, wid*32+32) of each tile.
    // one 16B/lane load covers 16 rows (row = r0+lane/4, kpart=(lane%4)*8)
    const int r0 = wid * 32;
    const int rA = r0 + (lane >> 2);
    const int kp = (lane & 3) * 8;

    const unsigned short* Ap0 = Abf + (size_t)(m0 + rA) * HIDDIM + kp;
    const unsigned short* Ap1 = Abf + (size_t)(m0 + rA + 16) * HIDDIM + kp;
    const unsigned short* Bp0 = Wbf + (size_t)(n0 + rA) * HIDDIM + kp;
    const unsigned short* Bp1 = Wbf + (size_t)(n0 + rA + 16) * HIDDIM + kp;

    unsigned short* AsD0 = &As[r0 * TBK];
    unsigned short* AsD1 = &As[(r0 + 16) * TBK];
    unsigned short* BsD0 = &Bs[r0 * TBK];
    unsigned short* BsD1 = &Bs[(r0 + 16) * TBK];

    const int fm = lane & 15;          // row within 16x16
    const int fk = (lane >> 4) * 8;    // k offset of fragment

    for (int k0 = 0; k0 < HIDDIM; k0 += TBK) {
        __syncthreads();               // prior LDS reads done before overwrite
        GLD16(Ap0 + k0, AsD0);
        GLD16(Ap1 + k0, AsD1);
        GLD16(Bp0 + k0, BsD0);
        GLD16(Bp1 + k0, BsD1);
        __syncthreads();               // barrier drains vmcnt -> tiles ready

        bf16x8 af[4], bfr[4];
        #pragma unroll
        for (int mi = 0; mi < 4; ++mi)
            af[mi] = *reinterpret_cast<const bf16x8*>(&As[(wm + mi * 16 + fm) * TBK + fk]);
        #pragma unroll
        for (int ni = 0; ni < 4; ++ni)
            bfr[ni] = *reinterpret_cast<const bf16x8*>(&Bs[(wn + ni * 16 + fm) * TBK + fk]);
        #pragma unroll
        for (int mi = 0; mi < 4; ++mi)
            #pragma unroll
            for (int ni = 0; ni < 4; ++ni)
                acc[mi][ni] = __builtin_amdgcn_mfma_f32_16x16x32_bf16(
                    af[mi], bfr[ni], acc[mi][ni], 0, 0, 0);
    }

    // epilogue: bias + relu; C/D layout col=lane&15, row=(lane>>4)*4+reg
    const bool isK = (n0 < HIDDIM);
    float* __restrict__ dst = isK ? K1 : V1;
    const int nsub = isK ? 0 : HIDDIM;

    #pragma unroll
    for (int ni = 0; ni < 4; ++ni) {
        const int ng = n0 + wn + ni * 16 + (lane & 15);
        const float bv = biasp[ng];
        const int col = ng - nsub;
        #pragma unroll
        for (int mi = 0; mi < 4; ++mi) {
            const int mb = m0 + wm + mi * 16 + (lane >> 4) * 4;
            #pragma unroll
            for (int r = 0; r < 4; ++r)
                dst[(size_t)(mb + r) * HIDDIM + col] = fmaxf(acc[mi][ni][r] + bv, 0.f);
        }
    }
}

// ---------------------------------------------------------------------------
// Kernel 2: per (b,h): scores -> softmax(+exp(-m)) -> events -> scans -> idx.
// 512 threads = 8 waves; wave-shuffle scans + 8-entry cross-wave combine.
// ---------------------------------------------------------------------------
#define SINF (1 << 30)

__global__ __launch_bounds__(512) void scores_scan(
    const float* __restrict__ K1,
    const float* __restrict__ rh,
    int* __restrict__ idxbuf)
{
    const int bh   = blockIdx.x;       // 0..191
    const int b    = bh / NH;
    const int h    = bh % NH;
    const int l    = threadIdx.x;      // 0..511
    const int lane = l & 63;
    const int wid  = l >> 6;

    __shared__ float wredA[8];
    __shared__ float wredB[8];
    __shared__ int   wp0[8];
    __shared__ int   wp1[8];
    __shared__ int   wp2[8];
    __shared__ int   ev[LQ];
    __shared__ int   col0[LQ];
    __shared__ int   col1[LQ];
    __shared__ int   E[LQ];

    // ---- 1. score ----
    const float* krow = K1 + ((size_t)(b * LQ + l)) * HIDDIM + h * HD;
    const float* rrow = rh + h * HD;
    float s = 0.f;
    #pragma unroll
    for (int d = 0; d < HD; d += 4) {
        float4 kv = *(const float4*)(krow + d);
        float4 rv = *(const float4*)(rrow + d);
        s += kv.x * rv.x + kv.y * rv.y + kv.z * rv.z + kv.w * rv.w;
    }

    // ---- 2. max reduce ----
    float mx = s;
    #pragma unroll
    for (int off = 32; off > 0; off >>= 1) mx = fmaxf(mx, __shfl_xor(mx, off));
    if (lane == 0) wredA[wid] = mx;
    __syncthreads();                               // B1
    float m = wredA[0];
    #pragma unroll
    for (int i = 1; i < 8; ++i) m = fmaxf(m, wredA[i]);

    // ---- 3. sum reduce ----
    const float e = expf(s - m);
    float sm = e;
    #pragma unroll
    for (int off = 32; off > 0; off >>= 1) sm += __shfl_xor(sm, off);
    if (lane == 0) wredB[wid] = sm;
    __syncthreads();                               // B2
    float ssum = 0.f;
    #pragma unroll
    for (int i = 0; i < 8; ++i) ssum += wredB[i];

    const float p = e / ssum + expf(-m);
    const int event = (p > (1.5f / 512.0f)) ? 1 : 0;
    ev[l] = event;                                 // visible after B3

    // ---- 4. col0: inclusive max-scan of (event ? l : -1) ----
    int v = event ? l : -1;
    #pragma unroll
    for (int off = 1; off < 64; off <<= 1) {
        int u = __shfl_up(v, off);
        if (lane >= off) v = (u > v) ? u : v;
    }
    if (lane == 63) wp0[wid] = v;
    __syncthreads();                               // B3
    int pfx = -1;
    for (int i = 0; i < wid; ++i) pfx = (wp0[i] > pfx) ? wp0[i] : pfx;
    v = (pfx > v) ? pfx : v;
    col0[l] = (v >= 0) ? v : l;                    // visible after B4

    // ---- 5. col1: suffix min-scan of (ev[(l+1)&511] ? l : INF) ----
    int v1 = ev[(l + 1) & (LQ - 1)] ? l : SINF;    // ev visible (B3)
    #pragma unroll
    for (int off = 1; off < 64; off <<= 1) {
        int u = __shfl_down(v1, off);
        if (lane < 64 - off) v1 = (u < v1) ? u : v1;
    }
    if (lane == 0) wp1[wid] = v1;
    __syncthreads();                               // B4
    int sfx = SINF;
    for (int i = wid + 1; i < 8; ++i) sfx = (wp1[i] < sfx) ? wp1[i] : sfx;
    v1 = (sfx < v1) ? sfx : v1;
    col1[l] = (l == 0) ? 0 : (((v1 < SINF) ? v1 : l) + 1);  // visible after B5

    // ---- 6. prefix count of events over steps 1..l (inclusive) ----
    int c = (l >= 1) ? event : 0;
    #pragma unroll
    for (int off = 1; off < 64; off <<= 1) {
        int u = __shfl_up(c, off);
        if (lane >= off) c += u;
    }
    if (lane == 63) wp2[wid] = c;
    __syncthreads();                               // B5
    for (int i = 0; i < wid; ++i) c += wp2[i];

    // ---- 7. event-time list ----
    if (l >= 1 && event) E[c - 1] = l;
    __syncthreads();                               // B6: E, col0, col1 ready

    // ---- 8. registers at l = pairs from last 8 event times <= l ----
    int* op = idxbuf + ((size_t)(b * LQ + l) * NH + h) * R2V;
    #pragma unroll
    for (int j = 0; j < 8; ++j) {
        const int k = c - 1 - j;
        int f = 0, bb = 0;
        if (k >= 0) {
            const int t = E[k];        // t >= 1
            f  = col0[t - 1];
            bb = col1[t - 1];
        }
        f  = min(max(f, 0), LQ - 1);
        bb = min(max(bb, 0), LQ - 1);
        op[2 * j]     = f;
        op[2 * j + 1] = bb;
    }
}

// ---------------------------------------------------------------------------
// Kernel 3: out[b,l,h,:] = sum_r w[h,r] * V1[b, idx[b,l,h,r], h, :]
// 16 lanes x float4 per (b,l,h); 16 groups per 256-thread block.
// ---------------------------------------------------------------------------
__global__ __launch_bounds__(256) void gather_out(
    const float* __restrict__ V1,
    const int* __restrict__ idxbuf,
    const float* __restrict__ w,
    float* __restrict__ out)
{
    const int g   = blockIdx.x * 16 + (threadIdx.x >> 4);  // (b*512+l)*12+h
    const int t16 = threadIdx.x & 15;
    const int h   = g % NH;
    const int bl  = g / NH;
    const int b   = bl / LQ;

    const int*   ip = idxbuf + (size_t)g * R2V;
    const float* wp = w + h * R2V;

    const int   myidx = ip[t16];
    const float myw   = wp[t16];

    const float* base = V1 + (size_t)b * LQ * HIDDIM + h * HD + t16 * 4;

    float4 acc = make_float4(0.f, 0.f, 0.f, 0.f);
    #pragma unroll
    for (int r = 0; r < R2V; ++r) {
        const int   idx = __shfl(myidx, r, 16);
        const float wr  = __shfl(myw,   r, 16);
        float4 v = *(const float4*)(base + (size_t)idx * HIDDIM);
        acc.x += wr * v.x; acc.y += wr * v.y;
        acc.z += wr * v.z; acc.w += wr * v.w;
    }
    *(float4*)(out + (size_t)g * HD + t16 * 4) = acc;
}

// ---------------------------------------------------------------------------
extern "C" void kernel_launch(void* const* d_in, const int* in_sizes, int n_in,
                              void* d_out, int out_size, void* d_ws, size_t ws_size,
                              hipStream_t stream)
{
    (void)in_sizes; (void)n_in; (void)out_size; (void)ws_size;

    const float* hs = (const float*)d_in[0];   // (16,512,768)
    const float* Kw = (const float*)d_in[1];   // (768,768)
    const float* Kb = (const float*)d_in[2];   // (768,)
    const float* Vw = (const float*)d_in[3];   // (768,768)
    const float* Vb = (const float*)d_in[4];   // (768,)
    const float* rh = (const float*)d_in[5];   // (12,64)
    const float* bw = (const float*)d_in[6];   // (1,1,12,1,16)
    float* out = (float*)d_out;                // (16,512,12,64) fp32

    // ws layout (bytes):
    //   K1   fp32 8192*768          @ 0         (25.17 MB)
    //   V1   fp32 8192*768          @ 25165824  (25.17 MB)
    //   idx  int  8192*12*16        @ 50331648  ( 6.29 MB)
    //   hsb  bf16 8192*768          @ 56623104  (12.58 MB)
    //   Wb   bf16 1536*768          @ 69206016  ( 2.36 MB)
    //   bias fp32 1536              @ 71565312  ( 6 KB)
    char* ws = (char*)d_ws;
    float*          K1    = (float*)(ws);
    float*          V1    = (float*)(ws + 25165824);
    int*            idxb  = (int*)  (ws + 50331648);
    unsigned short* hsb   = (unsigned short*)(ws + 56623104);
    unsigned short* Wb    = (unsigned short*)(ws + 69206016);
    float*          biasp = (float*)(ws + 71565312);

    cast_pack<<<(NHS4 + NW4) / 256, 256, 0, stream>>>(hs, Kw, Vw, Kb, Vb, hsb, Wb, biasp);

    dim3 g1(NTOT / TBN, MTOT / TBM);   // 12 x 64
    gemm_mfma<<<g1, 256, 0, stream>>>(hsb, Wb, biasp, K1, V1);

    scores_scan<<<BSZ * NH, LQ, 0, stream>>>(K1, rh, idxb);

    gather_out<<<(BSZ * LQ * NH) / 16, 256, 0, stream>>>(V1, idxb, bw, out);
}

// Round 3
// 147.275 us; speedup vs baseline: 2.7008x; 1.1478x over previous
//
#include <hip/hip_runtime.h>
#include <cstdint>
#include <cstddef>

#define BSZ 16
#define LQ  512
#define HIDDIM 768
#define NH  12
#define HD  64
#define R2V 16
#define NTOT 1536   // fused N: K cols [0,768) | V cols [768,1536)
#define MTOT 8192   // BSZ*LQ

typedef __bf16 bf16x8 __attribute__((ext_vector_type(8)));
typedef float  f32x4  __attribute__((ext_vector_type(4)));

__device__ inline unsigned short f2bf(float x) {
    union { float f; unsigned u; } c; c.f = x;
    unsigned r = c.u + 0x7fffu + ((c.u >> 16) & 1u);   // RNE (no NaN here)
    return (unsigned short)(r >> 16);
}
__device__ inline float bfl(unsigned u) { return __uint_as_float(u << 16); }
__device__ inline float bfh(unsigned u) { return __uint_as_float(u & 0xffff0000u); }

// ---------------------------------------------------------------------------
// Kernel 0: cast hs + pack weights (K rows then V rows) to bf16; pack bias.
// ---------------------------------------------------------------------------
#define NHS4 1572864   // 16*512*768/4
#define NW1  147456    // 768*768/4
#define NW4  294912    // 2*768*768/4

__global__ __launch_bounds__(256) void cast_pack(
    const float* __restrict__ hs,
    const float* __restrict__ Kw, const float* __restrict__ Vw,
    const float* __restrict__ Kb, const float* __restrict__ Vb,
    unsigned short* __restrict__ hsb, unsigned short* __restrict__ Wb,
    float* __restrict__ biasp)
{
    const int i = blockIdx.x * 256 + threadIdx.x;
    float4 v; unsigned short* dst;
    if (i < NHS4) {
        v = ((const float4*)hs)[i];
        dst = hsb + (size_t)i * 4;
    } else {
        const int j = i - NHS4;
        v = (j < NW1) ? ((const float4*)Kw)[j] : ((const float4*)Vw)[j - NW1];
        dst = Wb + (size_t)j * 4;
    }
    ushort4 o;
    o.x = f2bf(v.x); o.y = f2bf(v.y); o.z = f2bf(v.z); o.w = f2bf(v.w);
    *(ushort4*)dst = o;
    if (i < 768) { biasp[i] = Kb[i]; biasp[768 + i] = Vb[i]; }
}

// ---------------------------------------------------------------------------
// Kernel 1: bf16 MFMA GEMM -> bf16 outputs.
// 128x128 tile, BK=32, 256 threads = 4 waves, 16x16x32 MFMA,
// global_load_lds width=16. Swapped-operand MFMA so the C/D layout puts
// 4 consecutive n in regs -> ushort4 stores in the epilogue.
// ---------------------------------------------------------------------------
#define TBM 128
#define TBN 128
#define TBK 32

#define GLD16(g, l) __builtin_amdgcn_global_load_lds( \
    (const __attribute__((address_space(1))) void*)(g), \
    (__attribute__((address_space(3))) void*)(l), 16, 0, 0)

__global__ __launch_bounds__(256) void gemm_mfma(
    const unsigned short* __restrict__ Abf,   // 8192 x 768 bf16
    const unsigned short* __restrict__ Wbf,   // 1536 x 768 bf16
    const float* __restrict__ biasp,          // 1536 fp32
    unsigned short* __restrict__ K1b, unsigned short* __restrict__ V1b)
{
    __shared__ unsigned short As[TBM * TBK];  // 8 KB
    __shared__ unsigned short Bs[TBN * TBK];  // 8 KB

    const int n0   = blockIdx.x * TBN;
    const int m0   = blockIdx.y * TBM;
    const int tid  = threadIdx.x;
    const int wid  = tid >> 6;
    const int lane = tid & 63;
    const int wm   = (wid & 1) * 64;
    const int wn   = (wid >> 1) * 64;

    f32x4 acc[4][4] = {};   // [mi][ni]; lane holds m=lane&15, n-quad=(lane>>4)*4

    const int r0 = wid * 32;
    const int rA = r0 + (lane >> 2);
    const int kp = (lane & 3) * 8;

    const unsigned short* Ap0 = Abf + (size_t)(m0 + rA) * HIDDIM + kp;
    const unsigned short* Ap1 = Abf + (size_t)(m0 + rA + 16) * HIDDIM + kp;
    const unsigned short* Bp0 = Wbf + (size_t)(n0 + rA) * HIDDIM + kp;
    const unsigned short* Bp1 = Wbf + (size_t)(n0 + rA + 16) * HIDDIM + kp;

    unsigned short* AsD0 = &As[r0 * TBK];
    unsigned short* AsD1 = &As[(r0 + 16) * TBK];
    unsigned short* BsD0 = &Bs[r0 * TBK];
    unsigned short* BsD1 = &Bs[(r0 + 16) * TBK];

    const int fm = lane & 15;
    const int fk = (lane >> 4) * 8;

    for (int k0 = 0; k0 < HIDDIM; k0 += TBK) {
        __syncthreads();
        GLD16(Ap0 + k0, AsD0);
        GLD16(Ap1 + k0, AsD1);
        GLD16(Bp0 + k0, BsD0);
        GLD16(Bp1 + k0, BsD1);
        __syncthreads();

        bf16x8 af[4], bfr[4];
        #pragma unroll
        for (int mi = 0; mi < 4; ++mi)
            af[mi] = *reinterpret_cast<const bf16x8*>(&As[(wm + mi * 16 + fm) * TBK + fk]);
        #pragma unroll
        for (int ni = 0; ni < 4; ++ni)
            bfr[ni] = *reinterpret_cast<const bf16x8*>(&Bs[(wn + ni * 16 + fm) * TBK + fk]);
        #pragma unroll
        for (int mi = 0; mi < 4; ++mi)
            #pragma unroll
            for (int ni = 0; ni < 4; ++ni)
                acc[mi][ni] = __builtin_amdgcn_mfma_f32_16x16x32_bf16(
                    bfr[ni], af[mi], acc[mi][ni], 0, 0, 0);   // swapped: C^T layout
    }

    // epilogue: lane holds m = lane&15, n = (lane>>4)*4 + r (4 consecutive)
    const bool isK = (n0 < HIDDIM);
    unsigned short* __restrict__ dst = isK ? K1b : V1b;
    const int nsub = isK ? 0 : HIDDIM;
    const int mloc = lane & 15;
    const int nq   = (lane >> 4) * 4;

    #pragma unroll
    for (int mi = 0; mi < 4; ++mi) {
        const int mg = m0 + wm + mi * 16 + mloc;
        #pragma unroll
        for (int ni = 0; ni < 4; ++ni) {
            const int ng = n0 + wn + ni * 16 + nq;
            float4 bv = *(const float4*)(biasp + ng);
            f32x4 a = acc[mi][ni];
            ushort4 o;
            o.x = f2bf(fmaxf(a[0] + bv.x, 0.f));
            o.y = f2bf(fmaxf(a[1] + bv.y, 0.f));
            o.z = f2bf(fmaxf(a[2] + bv.z, 0.f));
            o.w = f2bf(fmaxf(a[3] + bv.w, 0.f));
            *(ushort4*)(dst + (size_t)mg * HIDDIM + (ng - nsub)) = o;
        }
    }
}

// ---------------------------------------------------------------------------
// Kernel 2: fused per (b,h): scores -> softmax(+exp(-m)) -> events -> scans
// -> idx (LDS) -> gather from V1b (global, L2-resident) -> out.
// 512 threads = 8 waves per block; 192 blocks.
// ---------------------------------------------------------------------------
#define SINF (1 << 30)
#define IXP 17   // idxs row stride (pad 16->17 to spread banks)

__global__ __launch_bounds__(512) void scan_gather(
    const unsigned short* __restrict__ K1b,
    const unsigned short* __restrict__ V1b,
    const float* __restrict__ rh,
    const float* __restrict__ bw,
    float* __restrict__ out)
{
    const int bh   = blockIdx.x;       // 0..191
    const int b    = bh / NH;
    const int h    = bh % NH;
    const int l    = threadIdx.x;      // 0..511
    const int lane = l & 63;
    const int wid  = l >> 6;

    __shared__ float wredA[8];
    __shared__ float wredB[8];
    __shared__ int   wp0[8];
    __shared__ int   wp1[8];
    __shared__ int   wp2[8];
    __shared__ int   ev[LQ];
    __shared__ int   col0[LQ];
    __shared__ int   col1[LQ];
    __shared__ int   E[LQ];
    __shared__ int   idxs[LQ * IXP];   // ~34.8 KB
    __shared__ float wsm[R2V];

    if (l < R2V) wsm[l] = bw[h * R2V + l];

    // ---- 1. score: dot64(bf16 K1 row, fp32 reading_head) ----
    const unsigned short* krow = K1b + ((size_t)(b * LQ + l)) * HIDDIM + h * HD;
    const float* rrow = rh + h * HD;
    float s = 0.f;
    #pragma unroll
    for (int c8 = 0; c8 < 8; ++c8) {
        uint4 kv = *(const uint4*)(krow + c8 * 8);
        float4 ra = *(const float4*)(rrow + c8 * 8);
        float4 rb = *(const float4*)(rrow + c8 * 8 + 4);
        s += bfl(kv.x) * ra.x + bfh(kv.x) * ra.y
           + bfl(kv.y) * ra.z + bfh(kv.y) * ra.w
           + bfl(kv.z) * rb.x + bfh(kv.z) * rb.y
           + bfl(kv.w) * rb.z + bfh(kv.w) * rb.w;
    }

    // ---- 2. max reduce ----
    float mx = s;
    #pragma unroll
    for (int off = 32; off > 0; off >>= 1) mx = fmaxf(mx, __shfl_xor(mx, off));
    if (lane == 0) wredA[wid] = mx;
    __syncthreads();
    float m = wredA[0];
    #pragma unroll
    for (int i = 1; i < 8; ++i) m = fmaxf(m, wredA[i]);

    // ---- 3. sum reduce ----
    const float e = expf(s - m);
    float sm = e;
    #pragma unroll
    for (int off = 32; off > 0; off >>= 1) sm += __shfl_xor(sm, off);
    if (lane == 0) wredB[wid] = sm;
    __syncthreads();
    float ssum = 0.f;
    #pragma unroll
    for (int i = 0; i < 8; ++i) ssum += wredB[i];

    const float p = e / ssum + expf(-m);
    const int event = (p > (1.5f / 512.0f)) ? 1 : 0;
    ev[l] = event;

    // ---- 4. col0: inclusive max-scan of (event ? l : -1) ----
    int v = event ? l : -1;
    #pragma unroll
    for (int off = 1; off < 64; off <<= 1) {
        int u = __shfl_up(v, off);
        if (lane >= off) v = (u > v) ? u : v;
    }
    if (lane == 63) wp0[wid] = v;
    __syncthreads();                     // ev + wp0 visible
    int pfx = -1;
    for (int i = 0; i < wid; ++i) pfx = (wp0[i] > pfx) ? wp0[i] : pfx;
    v = (pfx > v) ? pfx : v;
    col0[l] = (v >= 0) ? v : l;

    // ---- 5. col1: suffix min-scan of (ev[(l+1)&511] ? l : INF) ----
    int v1 = ev[(l + 1) & (LQ - 1)] ? l : SINF;
    #pragma unroll
    for (int off = 1; off < 64; off <<= 1) {
        int u = __shfl_down(v1, off);
        if (lane < 64 - off) v1 = (u < v1) ? u : v1;
    }
    if (lane == 0) wp1[wid] = v1;
    __syncthreads();
    int sfx = SINF;
    for (int i = wid + 1; i < 8; ++i) sfx = (wp1[i] < sfx) ? wp1[i] : sfx;
    v1 = (sfx < v1) ? sfx : v1;
    col1[l] = (l == 0) ? 0 : (((v1 < SINF) ? v1 : l) + 1);

    // ---- 6. prefix count of events over steps 1..l ----
    int c = (l >= 1) ? event : 0;
    #pragma unroll
    for (int off = 1; off < 64; off <<= 1) {
        int u = __shfl_up(c, off);
        if (lane >= off) c += u;
    }
    if (lane == 63) wp2[wid] = c;
    __syncthreads();
    for (int i = 0; i < wid; ++i) c += wp2[i];

    // ---- 7. event-time list ----
    if (l >= 1 && event) E[c - 1] = l;
    __syncthreads();                     // E, col0, col1 ready

    // ---- 8. idx registers -> LDS ----
    int* op = &idxs[l * IXP];
    #pragma unroll
    for (int j = 0; j < 8; ++j) {
        const int k = c - 1 - j;
        int f = 0, bb = 0;
        if (k >= 0) {
            const int t = E[k];          // t >= 1
            f  = col0[t - 1];
            bb = col1[t - 1];
        }
        op[2 * j]     = min(max(f, 0), LQ - 1);
        op[2 * j + 1] = min(max(bb, 0), LQ - 1);
    }
    __syncthreads();                     // idxs + wsm ready

    // ---- 9. gather: 8 lanes per l (dsl = lane&7 covers 8 d's), 8 rounds ----
    const int dsl = lane & 7;
    const size_t vbase = (size_t)b * LQ * HIDDIM + h * HD + dsl * 8;

    for (int round = 0; round < 8; ++round) {
        const int lg = round * 64 + wid * 8 + (lane >> 3);
        const int* ip = &idxs[lg * IXP];
        float a0 = 0.f, a1 = 0.f, a2 = 0.f, a3 = 0.f;
        float a4 = 0.f, a5 = 0.f, a6 = 0.f, a7 = 0.f;
        #pragma unroll
        for (int r = 0; r < R2V; ++r) {
            const int row = ip[r];
            const float wr = wsm[r];
            uint4 vv = *(const uint4*)(V1b + vbase + (size_t)row * HIDDIM);
            a0 += wr * bfl(vv.x); a1 += wr * bfh(vv.x);
            a2 += wr * bfl(vv.y); a3 += wr * bfh(vv.y);
            a4 += wr * bfl(vv.z); a5 += wr * bfh(vv.z);
            a6 += wr * bfl(vv.w); a7 += wr * bfh(vv.w);
        }
        float* po = out + ((size_t)(b * LQ + lg) * NH + h) * HD + dsl * 8;
        *(float4*)po       = make_float4(a0, a1, a2, a3);
        *((float4*)po + 1) = make_float4(a4, a5, a6, a7);
    }
}

// ---------------------------------------------------------------------------
extern "C" void kernel_launch(void* const* d_in, const int* in_sizes, int n_in,
                              void* d_out, int out_size, void* d_ws, size_t ws_size,
                              hipStream_t stream)
{
    (void)in_sizes; (void)n_in; (void)out_size; (void)ws_size;

    const float* hs = (const float*)d_in[0];
    const float* Kw = (const float*)d_in[1];
    const float* Kb = (const float*)d_in[2];
    const float* Vw = (const float*)d_in[3];
    const float* Vb = (const float*)d_in[4];
    const float* rh = (const float*)d_in[5];
    const float* bw = (const float*)d_in[6];
    float* out = (float*)d_out;

    // ws layout (bytes):
    //   K1b  bf16 8192*768  @ 0         (12.58 MB)
    //   V1b  bf16 8192*768  @ 12582912  (12.58 MB)
    //   hsb  bf16 8192*768  @ 25165824  (12.58 MB)
    //   Wb   bf16 1536*768  @ 37748736  ( 2.36 MB)
    //   bias fp32 1536      @ 40108032  ( 6 KB)
    char* ws = (char*)d_ws;
    unsigned short* K1b   = (unsigned short*)(ws);
    unsigned short* V1b   = (unsigned short*)(ws + 12582912);
    unsigned short* hsb   = (unsigned short*)(ws + 25165824);
    unsigned short* Wb    = (unsigned short*)(ws + 37748736);
    float*          biasp = (float*)(ws + 40108032);

    cast_pack<<<(NHS4 + NW4) / 256, 256, 0, stream>>>(hs, Kw, Vw, Kb, Vb, hsb, Wb, biasp);

    dim3 g1(NTOT / TBN, MTOT / TBM);   // 12 x 64
    gemm_mfma<<<g1, 256, 0, stream>>>(hsb, Wb, biasp, K1b, V1b);

    scan_gather<<<BSZ * NH, LQ, 0, stream>>>(K1b, V1b, rh, bw, out);
}

// Round 4
// 145.564 us; speedup vs baseline: 2.7326x; 1.0118x over previous
//
#include <hip/hip_runtime.h>
#include <cstdint>
#include <cstddef>

#define BSZ 16
#define LQ  512
#define HIDDIM 768
#define NH  12
#define HD  64
#define R2V 16
#define NTOT 1536   // fused N: K cols [0,768) | V cols [768,1536)
#define MTOT 8192   // BSZ*LQ

typedef __bf16 bf16x8 __attribute__((ext_vector_type(8)));
typedef float  f32x4  __attribute__((ext_vector_type(4)));

__device__ inline unsigned short f2bf(float x) {
    union { float f; unsigned u; } c; c.f = x;
    unsigned r = c.u + 0x7fffu + ((c.u >> 16) & 1u);   // RNE (no NaN here)
    return (unsigned short)(r >> 16);
}
__device__ inline float bfl(unsigned u) { return __uint_as_float(u << 16); }
__device__ inline float bfh(unsigned u) { return __uint_as_float(u & 0xffff0000u); }

// ---------------------------------------------------------------------------
// Kernel 0: cast hs + pack weights (K rows then V rows) to bf16; pack bias.
// ---------------------------------------------------------------------------
#define NHS4 1572864   // 16*512*768/4
#define NW1  147456    // 768*768/4
#define NW4  294912    // 2*768*768/4

__global__ __launch_bounds__(256) void cast_pack(
    const float* __restrict__ hs,
    const float* __restrict__ Kw, const float* __restrict__ Vw,
    const float* __restrict__ Kb, const float* __restrict__ Vb,
    unsigned short* __restrict__ hsb, unsigned short* __restrict__ Wb,
    float* __restrict__ biasp)
{
    const int i = blockIdx.x * 256 + threadIdx.x;
    float4 v; unsigned short* dst;
    if (i < NHS4) {
        v = ((const float4*)hs)[i];
        dst = hsb + (size_t)i * 4;
    } else {
        const int j = i - NHS4;
        v = (j < NW1) ? ((const float4*)Kw)[j] : ((const float4*)Vw)[j - NW1];
        dst = Wb + (size_t)j * 4;
    }
    ushort4 o;
    o.x = f2bf(v.x); o.y = f2bf(v.y); o.z = f2bf(v.z); o.w = f2bf(v.w);
    *(ushort4*)dst = o;
    if (i < 768) { biasp[i] = Kb[i]; biasp[768 + i] = Vb[i]; }
}

// ---------------------------------------------------------------------------
// Kernel 1: bf16 MFMA GEMM -> bf16 outputs.
// 128x128 tile, BK=32, 256 threads = 4 waves, 16x16x32 MFMA.
// DOUBLE-BUFFERED LDS, one barrier per K-iter: the barrier at iter t drains
// the global_load_lds issued at iter t-1 (which overlapped iter t-1's MFMAs).
// Swapped-operand MFMA -> C^T layout -> ushort4 stores.
// ---------------------------------------------------------------------------
#define TBM 128
#define TBN 128
#define TBK 32
#define KITERS (HIDDIM / TBK)   // 24

#define GLD16(g, l) __builtin_amdgcn_global_load_lds( \
    (const __attribute__((address_space(1))) void*)(g), \
    (__attribute__((address_space(3))) void*)(l), 16, 0, 0)

__global__ __launch_bounds__(256) void gemm_mfma(
    const unsigned short* __restrict__ Abf,   // 8192 x 768 bf16
    const unsigned short* __restrict__ Wbf,   // 1536 x 768 bf16
    const float* __restrict__ biasp,          // 1536 fp32
    unsigned short* __restrict__ K1b, unsigned short* __restrict__ V1b)
{
    __shared__ unsigned short As[2][TBM * TBK];  // 2 x 8 KB
    __shared__ unsigned short Bs[2][TBN * TBK];  // 2 x 8 KB

    const int n0   = blockIdx.x * TBN;
    const int m0   = blockIdx.y * TBM;
    const int tid  = threadIdx.x;
    const int wid  = tid >> 6;
    const int lane = tid & 63;
    const int wm   = (wid & 1) * 64;
    const int wn   = (wid >> 1) * 64;

    f32x4 acc[4][4] = {};   // lane holds m=lane&15, n-quad=(lane>>4)*4 (C^T)

    // staging: wave wid covers rows [wid*32, wid*32+32) of each tile.
    // one GLD16: 64 lanes x 16B = 16 rows (row = lane/4, kpart = (lane%4)*8)
    const int r0 = wid * 32;
    const int rA = r0 + (lane >> 2);
    const int kp = (lane & 3) * 8;

    const unsigned short* Ap0 = Abf + (size_t)(m0 + rA) * HIDDIM + kp;
    const unsigned short* Ap1 = Abf + (size_t)(m0 + rA + 16) * HIDDIM + kp;
    const unsigned short* Bp0 = Wbf + (size_t)(n0 + rA) * HIDDIM + kp;
    const unsigned short* Bp1 = Wbf + (size_t)(n0 + rA + 16) * HIDDIM + kp;

    const int fm = lane & 15;
    const int fk = (lane >> 4) * 8;

#define STAGE(buf, kof)                                        \
    do {                                                       \
        GLD16(Ap0 + (kof), &As[buf][r0 * TBK]);                \
        GLD16(Ap1 + (kof), &As[buf][(r0 + 16) * TBK]);         \
        GLD16(Bp0 + (kof), &Bs[buf][r0 * TBK]);                \
        GLD16(Bp1 + (kof), &Bs[buf][(r0 + 16) * TBK]);         \
    } while (0)

    STAGE(0, 0);   // prologue: stage tile 0 into buf 0

    for (int it = 0; it < KITERS; ++it) {
        __syncthreads();   // drains stage(it) [vmcnt] + protects LDS reuse
        if (it + 1 < KITERS) STAGE((it + 1) & 1, (it + 1) * TBK);
        const int cb = it & 1;

        bf16x8 af[4], bfr[4];
        #pragma unroll
        for (int mi = 0; mi < 4; ++mi)
            af[mi] = *reinterpret_cast<const bf16x8*>(&As[cb][(wm + mi * 16 + fm) * TBK + fk]);
        #pragma unroll
        for (int ni = 0; ni < 4; ++ni)
            bfr[ni] = *reinterpret_cast<const bf16x8*>(&Bs[cb][(wn + ni * 16 + fm) * TBK + fk]);
        #pragma unroll
        for (int mi = 0; mi < 4; ++mi)
            #pragma unroll
            for (int ni = 0; ni < 4; ++ni)
                acc[mi][ni] = __builtin_amdgcn_mfma_f32_16x16x32_bf16(
                    bfr[ni], af[mi], acc[mi][ni], 0, 0, 0);   // swapped: C^T
    }
#undef STAGE

    // epilogue: lane holds m = lane&15, n = (lane>>4)*4 + r (4 consecutive)
    const bool isK = (n0 < HIDDIM);
    unsigned short* __restrict__ dst = isK ? K1b : V1b;
    const int nsub = isK ? 0 : HIDDIM;
    const int mloc = lane & 15;
    const int nq   = (lane >> 4) * 4;

    #pragma unroll
    for (int mi = 0; mi < 4; ++mi) {
        const int mg = m0 + wm + mi * 16 + mloc;
        #pragma unroll
        for (int ni = 0; ni < 4; ++ni) {
            const int ng = n0 + wn + ni * 16 + nq;
            float4 bv = *(const float4*)(biasp + ng);
            f32x4 a = acc[mi][ni];
            ushort4 o;
            o.x = f2bf(fmaxf(a[0] + bv.x, 0.f));
            o.y = f2bf(fmaxf(a[1] + bv.y, 0.f));
            o.z = f2bf(fmaxf(a[2] + bv.z, 0.f));
            o.w = f2bf(fmaxf(a[3] + bv.w, 0.f));
            *(ushort4*)(dst + (size_t)mg * HIDDIM + (ng - nsub)) = o;
        }
    }
}

// ---------------------------------------------------------------------------
// Kernel 2: fused per (b,h): scores -> softmax(+exp(-m)) -> events -> scans
// -> idx (LDS) -> gather from V1b -> out.  512 threads = 8 waves; 192 blocks.
// Gather chunked 4-deep (unroll 1 on chunk loop) to cap VGPR pressure.
// ---------------------------------------------------------------------------
#define SINF (1 << 30)
#define IXP 17   // idxs row stride (pad 16->17)

__global__ __launch_bounds__(512) void scan_gather(
    const unsigned short* __restrict__ K1b,
    const unsigned short* __restrict__ V1b,
    const float* __restrict__ rh,
    const float* __restrict__ bw,
    float* __restrict__ out)
{
    const int bh   = blockIdx.x;       // 0..191
    const int b    = bh / NH;
    const int h    = bh % NH;
    const int l    = threadIdx.x;      // 0..511
    const int lane = l & 63;
    const int wid  = l >> 6;

    __shared__ float wredA[8];
    __shared__ float wredB[8];
    __shared__ int   wp0[8];
    __shared__ int   wp1[8];
    __shared__ int   wp2[8];
    __shared__ int   ev[LQ];
    __shared__ int   col0[LQ];
    __shared__ int   col1[LQ];
    __shared__ int   E[LQ];
    __shared__ int   idxs[LQ * IXP];   // ~34.8 KB
    __shared__ float wsm[R2V];

    if (l < R2V) wsm[l] = bw[h * R2V + l];

    // ---- 1. score: dot64(bf16 K1 row, fp32 reading_head) ----
    const unsigned short* krow = K1b + ((size_t)(b * LQ + l)) * HIDDIM + h * HD;
    const float* rrow = rh + h * HD;
    float s = 0.f;
    #pragma unroll
    for (int c8 = 0; c8 < 8; ++c8) {
        uint4 kv = *(const uint4*)(krow + c8 * 8);
        float4 ra = *(const float4*)(rrow + c8 * 8);
        float4 rb = *(const float4*)(rrow + c8 * 8 + 4);
        s += bfl(kv.x) * ra.x + bfh(kv.x) * ra.y
           + bfl(kv.y) * ra.z + bfh(kv.y) * ra.w
           + bfl(kv.z) * rb.x + bfh(kv.z) * rb.y
           + bfl(kv.w) * rb.z + bfh(kv.w) * rb.w;
    }

    // ---- 2. max reduce ----
    float mx = s;
    #pragma unroll
    for (int off = 32; off > 0; off >>= 1) mx = fmaxf(mx, __shfl_xor(mx, off));
    if (lane == 0) wredA[wid] = mx;
    __syncthreads();
    float m = wredA[0];
    #pragma unroll
    for (int i = 1; i < 8; ++i) m = fmaxf(m, wredA[i]);

    // ---- 3. sum reduce ----
    const float e = expf(s - m);
    float sm = e;
    #pragma unroll
    for (int off = 32; off > 0; off >>= 1) sm += __shfl_xor(sm, off);
    if (lane == 0) wredB[wid] = sm;
    __syncthreads();
    float ssum = 0.f;
    #pragma unroll
    for (int i = 0; i < 8; ++i) ssum += wredB[i];

    const float p = e / ssum + expf(-m);
    const int event = (p > (1.5f / 512.0f)) ? 1 : 0;
    ev[l] = event;

    // ---- 4. col0: inclusive max-scan of (event ? l : -1) ----
    int v = event ? l : -1;
    #pragma unroll
    for (int off = 1; off < 64; off <<= 1) {
        int u = __shfl_up(v, off);
        if (lane >= off) v = (u > v) ? u : v;
    }
    if (lane == 63) wp0[wid] = v;
    __syncthreads();                     // ev + wp0 visible
    int pfx = -1;
    for (int i = 0; i < wid; ++i) pfx = (wp0[i] > pfx) ? wp0[i] : pfx;
    v = (pfx > v) ? pfx : v;
    col0[l] = (v >= 0) ? v : l;

    // ---- 5. col1: suffix min-scan of (ev[(l+1)&511] ? l : INF) ----
    int v1 = ev[(l + 1) & (LQ - 1)] ? l : SINF;
    #pragma unroll
    for (int off = 1; off < 64; off <<= 1) {
        int u = __shfl_down(v1, off);
        if (lane < 64 - off) v1 = (u < v1) ? u : v1;
    }
    if (lane == 0) wp1[wid] = v1;
    __syncthreads();
    int sfx = SINF;
    for (int i = wid + 1; i < 8; ++i) sfx = (wp1[i] < sfx) ? wp1[i] : sfx;
    v1 = (sfx < v1) ? sfx : v1;
    col1[l] = (l == 0) ? 0 : (((v1 < SINF) ? v1 : l) + 1);

    // ---- 6. prefix count of events over steps 1..l ----
    int c = (l >= 1) ? event : 0;
    #pragma unroll
    for (int off = 1; off < 64; off <<= 1) {
        int u = __shfl_up(c, off);
        if (lane >= off) c += u;
    }
    if (lane == 63) wp2[wid] = c;
    __syncthreads();
    for (int i = 0; i < wid; ++i) c += wp2[i];

    // ---- 7. event-time list ----
    if (l >= 1 && event) E[c - 1] = l;
    __syncthreads();                     // E, col0, col1 ready

    // ---- 8. idx registers -> LDS ----
    int* op = &idxs[l * IXP];
    #pragma unroll
    for (int j = 0; j < 8; ++j) {
        const int k = c - 1 - j;
        int f = 0, bb = 0;
        if (k >= 0) {
            const int t = E[k];          // t >= 1
            f  = col0[t - 1];
            bb = col1[t - 1];
        }
        op[2 * j]     = min(max(f, 0), LQ - 1);
        op[2 * j + 1] = min(max(bb, 0), LQ - 1);
    }
    __syncthreads();                     // idxs + wsm ready

    // ---- 9. gather: 8 lanes per l (dsl covers 8 d's), 8 rounds, 4-chunked ----
    const int dsl = lane & 7;
    const size_t vbase = (size_t)b * LQ * HIDDIM + h * HD + dsl * 8;

    for (int round = 0; round < 8; ++round) {
        const int lg = round * 64 + wid * 8 + (lane >> 3);
        const int* ip = &idxs[lg * IXP];
        float a0 = 0.f, a1 = 0.f, a2 = 0.f, a3 = 0.f;
        float a4 = 0.f, a5 = 0.f, a6 = 0.f, a7 = 0.f;
        #pragma unroll 1
        for (int rc = 0; rc < R2V; rc += 4) {
            const int i0 = ip[rc], i1 = ip[rc + 1], i2 = ip[rc + 2], i3 = ip[rc + 3];
            uint4 v0 = *(const uint4*)(V1b + vbase + (size_t)i0 * HIDDIM);
            uint4 vA = *(const uint4*)(V1b + vbase + (size_t)i1 * HIDDIM);
            uint4 vB = *(const uint4*)(V1b + vbase + (size_t)i2 * HIDDIM);
            uint4 vC = *(const uint4*)(V1b + vbase + (size_t)i3 * HIDDIM);
            const float w0 = wsm[rc], w1 = wsm[rc + 1], w2 = wsm[rc + 2], w3 = wsm[rc + 3];
            a0 += w0 * bfl(v0.x); a1 += w0 * bfh(v0.x);
            a2 += w0 * bfl(v0.y); a3 += w0 * bfh(v0.y);
            a4 += w0 * bfl(v0.z); a5 += w0 * bfh(v0.z);
            a6 += w0 * bfl(v0.w); a7 += w0 * bfh(v0.w);
            a0 += w1 * bfl(vA.x); a1 += w1 * bfh(vA.x);
            a2 += w1 * bfl(vA.y); a3 += w1 * bfh(vA.y);
            a4 += w1 * bfl(vA.z); a5 += w1 * bfh(vA.z);
            a6 += w1 * bfl(vA.w); a7 += w1 * bfh(vA.w);
            a0 += w2 * bfl(vB.x); a1 += w2 * bfh(vB.x);
            a2 += w2 * bfl(vB.y); a3 += w2 * bfh(vB.y);
            a4 += w2 * bfl(vB.z); a5 += w2 * bfh(vB.z);
            a6 += w2 * bfl(vB.w); a7 += w2 * bfh(vB.w);
            a0 += w3 * bfl(vC.x); a1 += w3 * bfh(vC.x);
            a2 += w3 * bfl(vC.y); a3 += w3 * bfh(vC.y);
            a4 += w3 * bfl(vC.z); a5 += w3 * bfh(vC.z);
            a6 += w3 * bfl(vC.w); a7 += w3 * bfh(vC.w);
        }
        float* po = out + ((size_t)(b * LQ + lg) * NH + h) * HD + dsl * 8;
        *(float4*)po       = make_float4(a0, a1, a2, a3);
        *((float4*)po + 1) = make_float4(a4, a5, a6, a7);
    }
}

// ---------------------------------------------------------------------------
extern "C" void kernel_launch(void* const* d_in, const int* in_sizes, int n_in,
                              void* d_out, int out_size, void* d_ws, size_t ws_size,
                              hipStream_t stream)
{
    (void)in_sizes; (void)n_in; (void)out_size; (void)ws_size;

    const float* hs = (const float*)d_in[0];
    const float* Kw = (const float*)d_in[1];
    const float* Kb = (const float*)d_in[2];
    const float* Vw = (const float*)d_in[3];
    const float* Vb = (const float*)d_in[4];
    const float* rh = (const float*)d_in[5];
    const float* bw = (const float*)d_in[6];
    float* out = (float*)d_out;

    // ws layout (bytes):
    //   K1b  bf16 8192*768  @ 0         (12.58 MB)
    //   V1b  bf16 8192*768  @ 12582912  (12.58 MB)
    //   hsb  bf16 8192*768  @ 25165824  (12.58 MB)
    //   Wb   bf16 1536*768  @ 37748736  ( 2.36 MB)
    //   bias fp32 1536      @ 40108032  ( 6 KB)
    char* ws = (char*)d_ws;
    unsigned short* K1b   = (unsigned short*)(ws);
    unsigned short* V1b   = (unsigned short*)(ws + 12582912);
    unsigned short* hsb   = (unsigned short*)(ws + 25165824);
    unsigned short* Wb    = (unsigned short*)(ws + 37748736);
    float*          biasp = (float*)(ws + 40108032);

    cast_pack<<<(NHS4 + NW4) / 256, 256, 0, stream>>>(hs, Kw, Vw, Kb, Vb, hsb, Wb, biasp);

    dim3 g1(NTOT / TBN, MTOT / TBM);   // 12 x 64
    gemm_mfma<<<g1, 256, 0, stream>>>(hsb, Wb, biasp, K1b, V1b);

    scan_gather<<<BSZ * NH, LQ, 0, stream>>>(K1b, V1b, rh, bw, out);
}